// Round 1
// baseline (2210.930 us; speedup 1.0000x reference)
//
#include <hip/hip_runtime.h>
#include <hip/hip_bf16.h>
#include <cstdint>
#include <cstddef>

// Problem constants
//   B=2 S=4096 DM=3584 H=112 DH=64 INNER=7168 CHUNK=256
//   GEMM1: [8192 x 3584] * [14336 x 3584]^T -> xz [8192 x 14336] (bf16)
//   scan:  y[s] = A*y[s-256] + 0.1*x[s]; y *= sigmoid(z); in-place into x half
//   GEMM2: [8192 x 7168 (lda 14336)] * [3584 x 7168]^T -> out [8192 x 3584] f32

typedef __bf16 bf16x8 __attribute__((ext_vector_type(8)));
typedef float f32x4 __attribute__((ext_vector_type(4)));
typedef unsigned short us8 __attribute__((ext_vector_type(8)));

__device__ __forceinline__ unsigned short f2bf(float f) {
  return __builtin_bit_cast(unsigned short, (__bf16)f);
}
__device__ __forceinline__ float bf2f(unsigned short u) {
  return (float)__builtin_bit_cast(__bf16, u);
}

// async global->LDS, 16B per lane; LDS dest is wave-uniform base + lane*16
__device__ __forceinline__ void async_lds16(const unsigned short* g, unsigned short* l) {
  __builtin_amdgcn_global_load_lds(
      (__attribute__((address_space(1))) void*)(size_t)(const void*)g,
      (__attribute__((address_space(3))) void*)l,
      16, 0, 0);
}

// ---------------- f32 -> bf16 cast (4 elems/thread) ----------------
__global__ __launch_bounds__(256) void cvt_f32_bf16(
    const float* __restrict__ src, unsigned short* __restrict__ dst, int n4) {
  int t = blockIdx.x * 256 + threadIdx.x;
  if (t >= n4) return;
  float4 v = reinterpret_cast<const float4*>(src)[t];
  ushort4 o;
  o.x = f2bf(v.x); o.y = f2bf(v.y); o.z = f2bf(v.z); o.w = f2bf(v.w);
  reinterpret_cast<ushort4*>(dst)[t] = o;
}

// ---------------- m97-style bf16 GEMM, C = A * B^T ----------------
// A: [M x lda] bf16 (row-major, K contiguous), B: [N x ldb] bf16, C: [M x N] ld=ldc
// tile 128x128, BK=32, 256 threads = 4 waves, each wave 64x64 via 4x4 MFMA 16x16x32
template <bool OUT_BF16>
__global__ __launch_bounds__(256) void gemm_bt(
    const unsigned short* __restrict__ A, const unsigned short* __restrict__ Bm,
    void* __restrict__ Cv, int K, int lda, int ldb, int ldc) {
  __shared__ __align__(16) unsigned short As[128 * 32];
  __shared__ __align__(16) unsigned short Bs[128 * 32];

  const int lane = threadIdx.x & 63;
  const int wave = threadIdx.x >> 6;
  const int bm = blockIdx.y * 128;
  const int bn = blockIdx.x * 128;

  // staging: wave w covers rows [w*32, w*32+32); lane i -> row i/4, kcol (i%4)*8
  const int srow = lane >> 2;
  const int scol = (lane & 3) * 8;
  const unsigned short* ga0 = A + (size_t)(bm + wave * 32 + srow) * lda + scol;
  const unsigned short* ga1 = ga0 + (size_t)16 * lda;
  const unsigned short* gb0 = Bm + (size_t)(bn + wave * 32 + srow) * ldb + scol;
  const unsigned short* gb1 = gb0 + (size_t)16 * ldb;
  unsigned short* lA0 = As + wave * 1024;  // 16 rows * 32 k * (issue)
  unsigned short* lA1 = lA0 + 512;
  unsigned short* lB0 = Bs + wave * 1024;
  unsigned short* lB1 = lB0 + 512;

  const int wm = wave & 1;       // wave's 64-row block
  const int wn = wave >> 1;      // wave's 64-col block
  const int l15 = lane & 15;
  const int kq = lane >> 4;      // k-quad: frag k = kq*8..+8

  const unsigned short* fa = As + (wm * 64 + l15) * 32 + kq * 8;
  const unsigned short* fb = Bs + (wn * 64 + l15) * 32 + kq * 8;

  f32x4 acc[4][4];
#pragma unroll
  for (int i = 0; i < 4; ++i)
#pragma unroll
    for (int j = 0; j < 4; ++j) acc[i][j] = (f32x4){0.f, 0.f, 0.f, 0.f};

  for (int k0 = 0; k0 < K; k0 += 32) {
    async_lds16(ga0, lA0);
    async_lds16(ga1, lA1);
    async_lds16(gb0, lB0);
    async_lds16(gb1, lB1);
    __syncthreads();  // drains vmcnt(0): LDS populated

    bf16x8 a[4], b[4];
#pragma unroll
    for (int i = 0; i < 4; ++i)
      a[i] = *reinterpret_cast<const bf16x8*>(fa + i * (16 * 32));
#pragma unroll
    for (int j = 0; j < 4; ++j)
      b[j] = *reinterpret_cast<const bf16x8*>(fb + j * (16 * 32));

#pragma unroll
    for (int i = 0; i < 4; ++i)
#pragma unroll
      for (int j = 0; j < 4; ++j)
        acc[i][j] = __builtin_amdgcn_mfma_f32_16x16x32_bf16(a[i], b[j], acc[i][j], 0, 0, 0);

    ga0 += 32; ga1 += 32; gb0 += 32; gb1 += 32;
    __syncthreads();  // all waves done reading before next stage overwrites
  }

  // epilogue: C/D layout col=lane&15, row=(lane>>4)*4+reg
#pragma unroll
  for (int i = 0; i < 4; ++i) {
#pragma unroll
    for (int j = 0; j < 4; ++j) {
      const int col = bn + wn * 64 + j * 16 + l15;
#pragma unroll
      for (int r = 0; r < 4; ++r) {
        const int row = bm + wm * 64 + i * 16 + kq * 4 + r;
        if (OUT_BF16)
          ((unsigned short*)Cv)[(size_t)row * ldc + col] = f2bf(acc[i][j][r]);
        else
          ((float*)Cv)[(size_t)row * ldc + col] = acc[i][j][r];
      }
    }
  }
}

// ---------------- chunked decay scan + sigmoid gate (in-place on x half) ----
// thread = (b, r in [0,256), i8 in [0,896)); 16 sequential chunk steps
__global__ __launch_bounds__(256) void scan_gate(
    unsigned short* __restrict__ xz, const float* __restrict__ A_log) {
  const int tid = blockIdx.x * 256 + threadIdx.x;   // 458752 total
  const int i8 = tid % 896;
  const int rb = tid / 896;
  const int r = rb & 255;
  const int b = rb >> 8;
  const int i = i8 * 8;
  const float Ah = __expf(-fabsf(A_log[i >> 6]));   // head = i/64

  float st[8];
#pragma unroll
  for (int j = 0; j < 8; ++j) st[j] = 0.f;

  const size_t base = ((size_t)b * 4096 + r) * 14336 + i;
#pragma unroll
  for (int c = 0; c < 16; ++c) {
    const size_t off = base + (size_t)c * (256 * 14336);
    us8 xr = *reinterpret_cast<const us8*>(xz + off);
    us8 zr = *reinterpret_cast<const us8*>(xz + off + 7168);
    us8 yo;
#pragma unroll
    for (int j = 0; j < 8; ++j) {
      st[j] = st[j] * Ah + 0.1f * bf2f(xr[j]);
      const float zv = bf2f(zr[j]);
      const float sg = 1.f / (1.f + __expf(-zv));
      yo[j] = f2bf(st[j] * sg);
    }
    *reinterpret_cast<us8*>(xz + off) = yo;  // y overwrites x slot
  }
}

extern "C" void kernel_launch(void* const* d_in, const int* in_sizes, int n_in,
                              void* d_out, int out_size, void* d_ws, size_t ws_size,
                              hipStream_t stream) {
  const float* hidden = (const float*)d_in[0];   // [2,4096,3584]
  const float* W_in   = (const float*)d_in[1];   // [14336,3584]
  const float* W_out  = (const float*)d_in[2];   // [3584,7168]
  const float* A_log  = (const float*)d_in[3];   // [112]

  // workspace layout (bf16 elems): hid | win | wout | xz   = 447.7 MB total
  unsigned short* hid_bf  = (unsigned short*)d_ws;
  unsigned short* win_bf  = hid_bf  + 29360128ull;   // 2*4096*3584
  unsigned short* wout_bf = win_bf  + 51380224ull;   // 14336*3584
  unsigned short* xz      = wout_bf + 25690112ull;   // 3584*7168; xz = 8192*14336

  cvt_f32_bf16<<<29360128 / 4 / 256, 256, 0, stream>>>(hidden, hid_bf, 29360128 / 4);
  cvt_f32_bf16<<<51380224 / 4 / 256, 256, 0, stream>>>(W_in, win_bf, 51380224 / 4);
  cvt_f32_bf16<<<25690112 / 4 / 256, 256, 0, stream>>>(W_out, wout_bf, 25690112 / 4);

  // GEMM1: xz = hidden * W_in^T   (M=8192, N=14336, K=3584)
  gemm_bt<true><<<dim3(14336 / 128, 8192 / 128), 256, 0, stream>>>(
      hid_bf, win_bf, xz, 3584, 3584, 3584, 14336);

  scan_gate<<<1792, 256, 0, stream>>>(xz, A_log);

  // GEMM2: out = y * W_out^T   (M=8192, N=3584, K=7168, A lda=14336)
  gemm_bt<false><<<dim3(3584 / 128, 8192 / 128), 256, 0, stream>>>(
      xz, wout_bf, d_out, 7168, 14336, 7168, 3584);
}

// Round 2
// 2184.913 us; speedup vs baseline: 1.0119x; 1.0119x over previous
//
#include <hip/hip_runtime.h>
#include <hip/hip_bf16.h>
#include <cstdint>
#include <cstddef>

// Problem constants
//   B=2 S=4096 DM=3584 H=112 DH=64 INNER=7168 CHUNK=256
//   GEMM1: [8192 x 3584] * [14336 x 3584]^T -> xz [8192 x 14336] (bf16)
//   scan:  y[s] = A*y[s-256] + 0.1*x[s]; y *= sigmoid(z); in-place into x half
//   GEMM2: [8192 x 7168 (lda 14336)] * [3584 x 7168]^T -> out [8192 x 3584] f32

typedef __bf16 bf16x8 __attribute__((ext_vector_type(8)));
typedef float f32x4 __attribute__((ext_vector_type(4)));
typedef unsigned short us8 __attribute__((ext_vector_type(8)));

__device__ __forceinline__ unsigned short f2bf(float f) {
  return __builtin_bit_cast(unsigned short, (__bf16)f);
}
__device__ __forceinline__ float bf2f(unsigned short u) {
  return (float)__builtin_bit_cast(__bf16, u);
}

// async global->LDS, 16B per lane; LDS dest is wave-uniform base + lane*16
__device__ __forceinline__ void async_lds16(const unsigned short* g, unsigned short* l) {
  __builtin_amdgcn_global_load_lds(
      (__attribute__((address_space(1))) void*)(size_t)(const void*)g,
      (__attribute__((address_space(3))) void*)l,
      16, 0, 0);
}

// ---------------- f32 -> bf16 cast (4 elems/thread) ----------------
__global__ __launch_bounds__(256) void cvt_f32_bf16(
    const float* __restrict__ src, unsigned short* __restrict__ dst, int n4) {
  int t = blockIdx.x * 256 + threadIdx.x;
  if (t >= n4) return;
  float4 v = reinterpret_cast<const float4*>(src)[t];
  ushort4 o;
  o.x = f2bf(v.x); o.y = f2bf(v.y); o.z = f2bf(v.z); o.w = f2bf(v.w);
  reinterpret_cast<ushort4*>(dst)[t] = o;
}

// ---------------- m97-style bf16 GEMM, C = A * B^T, XOR-swizzled LDS -------
// A: [M x lda] bf16 (row-major, K contiguous), B: [N x ldb] bf16, C: [M x N] ld=ldc
// tile 128x128, BK=32, 256 threads = 4 waves, each wave 64x64 via 4x4 MFMA 16x16x32.
// LDS layout: row r holds its four 16B k-granules permuted g' = g ^ ((r>>1)&3),
// so fragment reads (16 lanes per kq at 64B row stride) spread across all 8
// four-bank groups instead of 2 (was: 8-way conflict, 1.03e8 conflict cycles).
template <bool OUT_BF16>
__global__ __launch_bounds__(256) void gemm_bt(
    const unsigned short* __restrict__ A, const unsigned short* __restrict__ Bm,
    void* __restrict__ Cv, int K, int lda, int ldb, int ldc) {
  __shared__ __align__(16) unsigned short As[128 * 32];
  __shared__ __align__(16) unsigned short Bs[128 * 32];

  const int lane = threadIdx.x & 63;
  const int wave = threadIdx.x >> 6;
  const int bm = blockIdx.y * 128;
  const int bn = blockIdx.x * 128;

  // staging: wave w covers rows [w*32, w*32+32); lane i -> row i/4.
  // k-granule loaded = (i&3) ^ s(row), s(row) = (row>>1)&3 = (i>>3)&3
  // (row = w*32 [+16] + (i>>2); the +16/w*32 parts are 0 mod 4 after >>1).
  const int srow = lane >> 2;
  const int scol = (((lane & 3) ^ ((lane >> 3) & 3))) * 8;
  const unsigned short* ga0 = A + (size_t)(bm + wave * 32 + srow) * lda + scol;
  const unsigned short* ga1 = ga0 + (size_t)16 * lda;
  const unsigned short* gb0 = Bm + (size_t)(bn + wave * 32 + srow) * ldb + scol;
  const unsigned short* gb1 = gb0 + (size_t)16 * ldb;
  unsigned short* lA0 = As + wave * 1024;
  unsigned short* lA1 = lA0 + 512;
  unsigned short* lB0 = Bs + wave * 1024;
  unsigned short* lB1 = lB0 + 512;

  const int wm = wave & 1;       // wave's 64-row block
  const int wn = wave >> 1;      // wave's 64-col block
  const int l15 = lane & 15;
  const int kq = lane >> 4;      // k-quad: frag k = kq*8..+8

  // fragment read: row-local = (wm*64 + i*16) + l15; swizzled granule
  // g' = kq ^ ((l15>>1)&3)  (higher row bits are 0 mod 4 after >>1)
  const int gsw = (kq ^ ((l15 >> 1) & 3)) * 8;
  const unsigned short* fa = As + (wm * 64 + l15) * 32 + gsw;
  const unsigned short* fb = Bs + (wn * 64 + l15) * 32 + gsw;

  f32x4 acc[4][4];
#pragma unroll
  for (int i = 0; i < 4; ++i)
#pragma unroll
    for (int j = 0; j < 4; ++j) acc[i][j] = (f32x4){0.f, 0.f, 0.f, 0.f};

  for (int k0 = 0; k0 < K; k0 += 32) {
    async_lds16(ga0, lA0);
    async_lds16(ga1, lA1);
    async_lds16(gb0, lB0);
    async_lds16(gb1, lB1);
    __syncthreads();  // drains vmcnt(0): LDS populated

    bf16x8 a[4], b[4];
#pragma unroll
    for (int i = 0; i < 4; ++i)
      a[i] = *reinterpret_cast<const bf16x8*>(fa + i * (16 * 32));
#pragma unroll
    for (int j = 0; j < 4; ++j)
      b[j] = *reinterpret_cast<const bf16x8*>(fb + j * (16 * 32));

#pragma unroll
    for (int i = 0; i < 4; ++i)
#pragma unroll
      for (int j = 0; j < 4; ++j)
        acc[i][j] = __builtin_amdgcn_mfma_f32_16x16x32_bf16(a[i], b[j], acc[i][j], 0, 0, 0);

    ga0 += 32; ga1 += 32; gb0 += 32; gb1 += 32;
    __syncthreads();  // all waves done reading before next stage overwrites
  }

  // epilogue: C/D layout col=lane&15, row=(lane>>4)*4+reg
#pragma unroll
  for (int i = 0; i < 4; ++i) {
#pragma unroll
    for (int j = 0; j < 4; ++j) {
      const int col = bn + wn * 64 + j * 16 + l15;
#pragma unroll
      for (int r = 0; r < 4; ++r) {
        const int row = bm + wm * 64 + i * 16 + kq * 4 + r;
        if (OUT_BF16)
          ((unsigned short*)Cv)[(size_t)row * ldc + col] = f2bf(acc[i][j][r]);
        else
          ((float*)Cv)[(size_t)row * ldc + col] = acc[i][j][r];
      }
    }
  }
}

// ---------------- chunked decay scan + sigmoid gate (in-place on x half) ----
// thread = (b, r in [0,256), i8 in [0,896)); 16 sequential chunk steps
__global__ __launch_bounds__(256) void scan_gate(
    unsigned short* __restrict__ xz, const float* __restrict__ A_log) {
  const int tid = blockIdx.x * 256 + threadIdx.x;   // 458752 total
  const int i8 = tid % 896;
  const int rb = tid / 896;
  const int r = rb & 255;
  const int b = rb >> 8;
  const int i = i8 * 8;
  const float Ah = __expf(-fabsf(A_log[i >> 6]));   // head = i/64

  float st[8];
#pragma unroll
  for (int j = 0; j < 8; ++j) st[j] = 0.f;

  const size_t base = ((size_t)b * 4096 + r) * 14336 + i;
#pragma unroll
  for (int c = 0; c < 16; ++c) {
    const size_t off = base + (size_t)c * (256 * 14336);
    us8 xr = *reinterpret_cast<const us8*>(xz + off);
    us8 zr = *reinterpret_cast<const us8*>(xz + off + 7168);
    us8 yo;
#pragma unroll
    for (int j = 0; j < 8; ++j) {
      st[j] = st[j] * Ah + 0.1f * bf2f(xr[j]);
      const float zv = bf2f(zr[j]);
      const float sg = 1.f / (1.f + __expf(-zv));
      yo[j] = f2bf(st[j] * sg);
    }
    *reinterpret_cast<us8*>(xz + off) = yo;  // y overwrites x slot
  }
}

extern "C" void kernel_launch(void* const* d_in, const int* in_sizes, int n_in,
                              void* d_out, int out_size, void* d_ws, size_t ws_size,
                              hipStream_t stream) {
  const float* hidden = (const float*)d_in[0];   // [2,4096,3584]
  const float* W_in   = (const float*)d_in[1];   // [14336,3584]
  const float* W_out  = (const float*)d_in[2];   // [3584,7168]
  const float* A_log  = (const float*)d_in[3];   // [112]

  // workspace layout (bf16 elems): hid | win | wout | xz   = 447.7 MB total
  unsigned short* hid_bf  = (unsigned short*)d_ws;
  unsigned short* win_bf  = hid_bf  + 29360128ull;   // 2*4096*3584
  unsigned short* wout_bf = win_bf  + 51380224ull;   // 14336*3584
  unsigned short* xz      = wout_bf + 25690112ull;   // 3584*7168; xz = 8192*14336

  cvt_f32_bf16<<<29360128 / 4 / 256, 256, 0, stream>>>(hidden, hid_bf, 29360128 / 4);
  cvt_f32_bf16<<<51380224 / 4 / 256, 256, 0, stream>>>(W_in, win_bf, 51380224 / 4);
  cvt_f32_bf16<<<25690112 / 4 / 256, 256, 0, stream>>>(W_out, wout_bf, 25690112 / 4);

  // GEMM1: xz = hidden * W_in^T   (M=8192, N=14336, K=3584)
  gemm_bt<true><<<dim3(14336 / 128, 8192 / 128), 256, 0, stream>>>(
      hid_bf, win_bf, xz, 3584, 3584, 3584, 14336);

  scan_gate<<<1792, 256, 0, stream>>>(xz, A_log);

  // GEMM2: out = y * W_out^T   (M=8192, N=3584, K=7168, A lda=14336)
  gemm_bt<false><<<dim3(3584 / 128, 8192 / 128), 256, 0, stream>>>(
      xz, wout_bf, d_out, 7168, 14336, 7168, 3584);
}

// Round 3
// 1994.760 us; speedup vs baseline: 1.1084x; 1.0953x over previous
//
#include <hip/hip_runtime.h>
#include <hip/hip_bf16.h>
#include <cstdint>
#include <cstddef>

// Problem constants
//   B=2 S=4096 DM=3584 H=112 DH=64 INNER=7168 CHUNK=256
//   GEMM1: [8192 x 3584] * [14336 x 3584]^T -> xz [8192 x 14336] (bf16)
//   scan:  y[s] = A*y[s-256] + 0.1*x[s]; y *= sigmoid(z); in-place into x half
//   GEMM2: [8192 x 7168 (lda 14336)] * [3584 x 7168]^T -> out [8192 x 3584] f32

typedef __bf16 bf16x8 __attribute__((ext_vector_type(8)));
typedef float f32x4 __attribute__((ext_vector_type(4)));
typedef unsigned short us8 __attribute__((ext_vector_type(8)));

__device__ __forceinline__ unsigned short f2bf(float f) {
  return __builtin_bit_cast(unsigned short, (__bf16)f);
}
__device__ __forceinline__ float bf2f(unsigned short u) {
  return (float)__builtin_bit_cast(__bf16, u);
}

// async global->LDS, 16B per lane; LDS dest is wave-uniform base + lane*16
__device__ __forceinline__ void async_lds16(const unsigned short* g, unsigned short* l) {
  __builtin_amdgcn_global_load_lds(
      (__attribute__((address_space(1))) void*)(size_t)(const void*)g,
      (__attribute__((address_space(3))) void*)l,
      16, 0, 0);
}

// ---------------- f32 -> bf16 cast (4 elems/thread) ----------------
__global__ __launch_bounds__(256) void cvt_f32_bf16(
    const float* __restrict__ src, unsigned short* __restrict__ dst, int n4) {
  int t = blockIdx.x * 256 + threadIdx.x;
  if (t >= n4) return;
  float4 v = reinterpret_cast<const float4*>(src)[t];
  ushort4 o;
  o.x = f2bf(v.x); o.y = f2bf(v.y); o.z = f2bf(v.z); o.w = f2bf(v.w);
  reinterpret_cast<ushort4*>(dst)[t] = o;
}

// ---------------- bf16 GEMM, C = A * B^T, BK=64, XOR-swizzled LDS ----------
// A: [M x lda] bf16 (row-major, K contiguous), B: [N x ldb] bf16, C: [M x N] ld=ldc
// tile 128x128, BK=64 (32 MFMA per barrier pair), 256 threads = 4 waves,
// each wave 64x64 via 4x4 MFMA 16x16x32. LDS 32 KB (occupancy is VGPR-bound
// at 3 blocks/CU, so 32 KB is free — BK=128/64KB would drop to 2, m132).
// LDS swizzle: row r slot t holds global 16B-granule t ^ (r&7); row stride
// 128 B == 32 banks, so bank group == slot -> fragment reads uniform over all
// 8 four-bank groups (conflict-free, verified 0 conflicts in R2 pattern).
template <bool OUT_BF16>
__global__ __launch_bounds__(256) void gemm_bt(
    const unsigned short* __restrict__ A, const unsigned short* __restrict__ Bm,
    void* __restrict__ Cv, int K, int lda, int ldb, int ldc) {
  __shared__ __align__(16) unsigned short As[128 * 64];
  __shared__ __align__(16) unsigned short Bs[128 * 64];

  const int lane = threadIdx.x & 63;
  const int wave = threadIdx.x >> 6;
  const int bm = blockIdx.y * 128;
  const int bn = blockIdx.x * 128;

  // staging: wave w covers rows [w*32,(w+1)*32) in 4 instrs of 8 rows each.
  // lane i -> row (i>>3), LDS slot granule (i&7), global granule (i&7)^(i>>3)
  const int srow = lane >> 3;                  // 0..7
  const int scol = ((lane & 7) ^ srow) * 8;    // swizzled global column (elems)
  const unsigned short* gA = A + (size_t)(bm + wave * 32 + srow) * lda + scol;
  const unsigned short* gB = Bm + (size_t)(bn + wave * 32 + srow) * ldb + scol;
  unsigned short* lA = As + wave * 2048;       // 32 rows * 64 elems
  unsigned short* lB = Bs + wave * 2048;

  const int wm = wave & 1;       // wave's 64-row block
  const int wn = wave >> 1;      // wave's 64-col block
  const int l15 = lane & 15;
  const int kq = lane >> 4;      // k-quad within sub-k: frag k = sub*32+kq*8..+8
  const int s7 = l15 & 7;        // row&7 for fragment rows
  const int so0 = ((kq ^ s7) * 8);   // slot offset (elems) for sub 0
  // sub 1: global granule 4+kq = 4^kq (kq<4) -> slot = so0 ^ 32 elems

  const unsigned short* fa = As + (wm * 64 + l15) * 64;
  const unsigned short* fb = Bs + (wn * 64 + l15) * 64;

  f32x4 acc[4][4];
#pragma unroll
  for (int i = 0; i < 4; ++i)
#pragma unroll
    for (int j = 0; j < 4; ++j) acc[i][j] = (f32x4){0.f, 0.f, 0.f, 0.f};

  for (int k0 = 0; k0 < K; k0 += 64) {
#pragma unroll
    for (int j = 0; j < 4; ++j) {
      async_lds16(gA + (size_t)(j * 8) * lda, lA + j * 512);
      async_lds16(gB + (size_t)(j * 8) * ldb, lB + j * 512);
    }
    __syncthreads();  // drains vmcnt(0): LDS populated

#pragma unroll
    for (int sub = 0; sub < 2; ++sub) {
      const int so = so0 ^ (sub * 32);
      bf16x8 a[4], b[4];
#pragma unroll
      for (int i = 0; i < 4; ++i)
        a[i] = *reinterpret_cast<const bf16x8*>(fa + i * (16 * 64) + so);
#pragma unroll
      for (int j = 0; j < 4; ++j)
        b[j] = *reinterpret_cast<const bf16x8*>(fb + j * (16 * 64) + so);

#pragma unroll
      for (int i = 0; i < 4; ++i)
#pragma unroll
        for (int j = 0; j < 4; ++j)
          acc[i][j] = __builtin_amdgcn_mfma_f32_16x16x32_bf16(a[i], b[j], acc[i][j], 0, 0, 0);
    }

    gA += 64; gB += 64;
    __syncthreads();  // all waves done reading before next stage overwrites
  }

  // epilogue: C/D layout col=lane&15, row=(lane>>4)*4+reg
#pragma unroll
  for (int i = 0; i < 4; ++i) {
#pragma unroll
    for (int j = 0; j < 4; ++j) {
      const int col = bn + wn * 64 + j * 16 + l15;
#pragma unroll
      for (int r = 0; r < 4; ++r) {
        const int row = bm + wm * 64 + i * 16 + kq * 4 + r;
        if (OUT_BF16)
          ((unsigned short*)Cv)[(size_t)row * ldc + col] = f2bf(acc[i][j][r]);
        else
          ((float*)Cv)[(size_t)row * ldc + col] = acc[i][j][r];
      }
    }
  }
}

// ---------------- chunked decay scan + sigmoid gate (in-place on x half) ----
// thread = (b, r in [0,256), i8 in [0,896)); 16 sequential chunk steps
__global__ __launch_bounds__(256) void scan_gate(
    unsigned short* __restrict__ xz, const float* __restrict__ A_log) {
  const int tid = blockIdx.x * 256 + threadIdx.x;   // 458752 total
  const int i8 = tid % 896;
  const int rb = tid / 896;
  const int r = rb & 255;
  const int b = rb >> 8;
  const int i = i8 * 8;
  const float Ah = __expf(-fabsf(A_log[i >> 6]));   // head = i/64

  float st[8];
#pragma unroll
  for (int j = 0; j < 8; ++j) st[j] = 0.f;

  const size_t base = ((size_t)b * 4096 + r) * 14336 + i;
#pragma unroll
  for (int c = 0; c < 16; ++c) {
    const size_t off = base + (size_t)c * (256 * 14336);
    us8 xr = *reinterpret_cast<const us8*>(xz + off);
    us8 zr = *reinterpret_cast<const us8*>(xz + off + 7168);
    us8 yo;
#pragma unroll
    for (int j = 0; j < 8; ++j) {
      st[j] = st[j] * Ah + 0.1f * bf2f(xr[j]);
      const float zv = bf2f(zr[j]);
      const float sg = 1.f / (1.f + __expf(-zv));
      yo[j] = f2bf(st[j] * sg);
    }
    *reinterpret_cast<us8*>(xz + off) = yo;  // y overwrites x slot
  }
}

extern "C" void kernel_launch(void* const* d_in, const int* in_sizes, int n_in,
                              void* d_out, int out_size, void* d_ws, size_t ws_size,
                              hipStream_t stream) {
  const float* hidden = (const float*)d_in[0];   // [2,4096,3584]
  const float* W_in   = (const float*)d_in[1];   // [14336,3584]
  const float* W_out  = (const float*)d_in[2];   // [3584,7168]
  const float* A_log  = (const float*)d_in[3];   // [112]

  // workspace layout (bf16 elems): hid | win | wout | xz   = 447.7 MB total
  unsigned short* hid_bf  = (unsigned short*)d_ws;
  unsigned short* win_bf  = hid_bf  + 29360128ull;   // 2*4096*3584
  unsigned short* wout_bf = win_bf  + 51380224ull;   // 14336*3584
  unsigned short* xz      = wout_bf + 25690112ull;   // 3584*7168; xz = 8192*14336

  cvt_f32_bf16<<<29360128 / 4 / 256, 256, 0, stream>>>(hidden, hid_bf, 29360128 / 4);
  cvt_f32_bf16<<<51380224 / 4 / 256, 256, 0, stream>>>(W_in, win_bf, 51380224 / 4);
  cvt_f32_bf16<<<25690112 / 4 / 256, 256, 0, stream>>>(W_out, wout_bf, 25690112 / 4);

  // GEMM1: xz = hidden * W_in^T   (M=8192, N=14336, K=3584)
  gemm_bt<true><<<dim3(14336 / 128, 8192 / 128), 256, 0, stream>>>(
      hid_bf, win_bf, xz, 3584, 3584, 3584, 14336);

  scan_gate<<<1792, 256, 0, stream>>>(xz, A_log);

  // GEMM2: out = y * W_out^T   (M=8192, N=3584, K=7168, A lda=14336)
  gemm_bt<false><<<dim3(3584 / 128, 8192 / 128), 256, 0, stream>>>(
      xz, wout_bf, d_out, 7168, 14336, 7168, 3584);
}